// Round 1
// baseline (56.139 us; speedup 1.0000x reference)
//
#include <hip/hip_runtime.h>

#define BATCH  4
#define IN_CH  64
#define OUT_CH 128
#define HSZ    56
#define WSZ    56
#define HW     (HSZ * WSZ)   // 3136
#define OG     8             // output channels per block
#define SPT    448           // spatial pixels per block (8 rows), 3136 = 7*448

__global__ __launch_bounds__(SPT) void dissected_conv2d_direct(
    const float* __restrict__ x,     // [B, IN_CH, H, W]
    const float* __restrict__ Wt,    // [OUT_CH, IN_CH, 3, 3]
    const float* __restrict__ bias,  // [OUT_CH]
    float* __restrict__ out)         // [B, OUT_CH, H, W]
{
    const int tid   = threadIdx.x;
    const int s     = blockIdx.x * SPT + tid;   // 0..3135, exact fit
    const int obase = blockIdx.y * OG;
    const int bz    = blockIdx.z;

    const int h = s / WSZ;
    const int w = s - h * WSZ;

    // Precompute the 9 tap offsets (clamped) + validity masks once.
    int   off[9];
    float msk[9];
#pragma unroll
    for (int dh = 0; dh < 3; ++dh) {
#pragma unroll
        for (int dw = 0; dw < 3; ++dw) {
            const int hh = h + dh - 1;
            const int ww = w + dw - 1;
            const bool valid = (hh >= 0) && (hh < HSZ) && (ww >= 0) && (ww < WSZ);
            const int hc = min(max(hh, 0), HSZ - 1);
            const int wc = min(max(ww, 0), WSZ - 1);
            off[dh * 3 + dw] = hc * WSZ + wc;
            msk[dh * 3 + dw] = valid ? 1.0f : 0.0f;
        }
    }

    const float* xb = x + (size_t)bz * IN_CH * HW;

    float acc[OG];
#pragma unroll
    for (int oo = 0; oo < OG; ++oo) acc[oo] = 0.0f;

    for (int i = 0; i < IN_CH; ++i) {
        const float* xi = xb + i * HW;
        float xv[9];
#pragma unroll
        for (int p = 0; p < 9; ++p) xv[p] = xi[off[p]] * msk[p];

        // Weight index depends only on blockIdx.y + unrolled constants
        // -> block-uniform -> scalar (s_load) path expected.
#pragma unroll
        for (int oo = 0; oo < OG; ++oo) {
            const float* wp = Wt + ((size_t)(obase + oo) * IN_CH + i) * 9;
#pragma unroll
            for (int p = 0; p < 9; ++p)
                acc[oo] = fmaf(xv[p], wp[p], acc[oo]);
        }
    }

#pragma unroll
    for (int oo = 0; oo < OG; ++oo) {
        out[((size_t)(bz * OUT_CH + obase + oo)) * HW + s] = acc[oo] + bias[obase + oo];
    }
}

extern "C" void kernel_launch(void* const* d_in, const int* in_sizes, int n_in,
                              void* d_out, int out_size, void* d_ws, size_t ws_size,
                              hipStream_t stream) {
    const float* x    = (const float*)d_in[0];
    const float* Wt   = (const float*)d_in[1];
    const float* bias = (const float*)d_in[2];
    float* out        = (float*)d_out;

    dim3 grid(HW / SPT, OUT_CH / OG, BATCH);  // (7, 16, 4)
    dissected_conv2d_direct<<<grid, SPT, 0, stream>>>(x, Wt, bias, out);
}

// Round 2
// 31.706 us; speedup vs baseline: 1.7706x; 1.7706x over previous
//
#include <hip/hip_runtime.h>
#include <hip/hip_bf16.h>

#define BATCH 4
#define IC 64
#define OC 128
#define HSZ 56
#define WSZ 56
#define HW 3136          // 56*56
#define KTOT 576         // 9 taps * 64 in_ch
#define PTILE 64         // pixels per block (3136 = 49*64 exact)
#define HALO 57          // max |tap offset| = 56+1
#define XROWS 178        // PTILE + 2*HALO

typedef __attribute__((ext_vector_type(8))) short bf16x8;
typedef __attribute__((ext_vector_type(4))) float f32x4;

// Prep: W [128][64][3][3] f32  ->  Wb [o][k] bf16, k = tap*64 + ch (tap = kh*3+kw).
// Wb[o][k] is B^T storage: B-frag = 8 contiguous k at fixed o (m97-verified layout).
__global__ __launch_bounds__(256) void wcvt_kernel(const float* __restrict__ W,
                                                   unsigned short* __restrict__ Wb) {
    int idx = blockIdx.x * 256 + threadIdx.x;
    if (idx >= OC * KTOT) return;
    int o = idx / KTOT;
    int k = idx - o * KTOT;
    int tap = k >> 6;
    int ch = k & 63;
    float v = W[(o * IC + ch) * 9 + tap];
    __hip_bfloat16 h = __float2bfloat16(v);
    Wb[idx] = *reinterpret_cast<unsigned short*>(&h);
}

// Implicit-GEMM conv. Block: 64 pixels x 128 out_ch, 8 waves.
// Wave (pg, og): 16-pixel group pg (0..3), 64-outch half og (0..1).
__global__ __launch_bounds__(512) void conv_mfma_kernel(
    const float* __restrict__ x,             // [B][64][3136] f32
    const unsigned short* __restrict__ Wb,   // [128][576] bf16
    const float* __restrict__ bias,          // [128] f32
    float* __restrict__ out)                 // [B][128][3136] f32
{
    // x halo tile, [pix 0..177][ch 0..63] bf16, 8-ch chunks XOR-swizzled by (pix&7)
    // so A-frag ds_read_b128 is spread across banks.
    __shared__ unsigned short xs[XROWS * 64];   // 22.25 KB

    const int tid = threadIdx.x;
    const int b  = blockIdx.y;
    const int p0 = blockIdx.x * PTILE;

    const float* xb = x + (size_t)b * IC * HW;

    // ---- stage x halo: coalesced f32 reads (consecutive tid -> consecutive pix) ----
    for (int it = 0; it < 23; ++it) {           // 178*64 = 11392 = 22.25*512
        int idx = it * 512 + tid;
        if (idx < XROWS * IC) {
            int ch  = idx / XROWS;
            int pix = idx - ch * XROWS;
            int gp  = p0 - HALO + pix;
            gp = min(max(gp, 0), HW - 1);       // clamp; invalid taps get masked below
            float v = xb[ch * HW + gp];
            __hip_bfloat16 h = __float2bfloat16(v);
            int chunk = (ch >> 3) ^ (pix & 7);
            xs[pix * 64 + chunk * 8 + (ch & 7)] = *reinterpret_cast<unsigned short*>(&h);
        }
    }
    __syncthreads();

    const int lane = tid & 63;
    const int wid  = tid >> 6;
    const int pg   = wid & 3;
    const int og   = wid >> 2;
    const int lrow = lane & 15;    // A-row (pixel-in-group) / B-col (out_ch-in-group)
    const int lk   = lane >> 4;    // k-chunk 0..3

    const int tpix = pg * 16 + lrow;       // pixel within tile
    const int apix = p0 + tpix;            // absolute pixel in image
    const int ah = apix / WSZ;
    const int aw = apix - ah * WSZ;

    // per-(pixel,tap) validity: tap t=(dh+1)*3+(dw+1); flat-index shift crosses
    // row edges -> must zero the A-fragment for that tap.
    unsigned vmask = 0;
#pragma unroll
    for (int t = 0; t < 9; ++t) {
        int hh = ah + (t / 3) - 1;
        int ww = aw + (t % 3) - 1;
        if ((unsigned)hh < (unsigned)HSZ && (unsigned)ww < (unsigned)WSZ)
            vmask |= (1u << t);
    }

    // B base: Wb[o][k], o = og*64 + bg*16 + lrow, lane's k-chunk = 8*lk
    const unsigned short* wb = Wb + (size_t)(og * 64 + lrow) * KTOT + 8 * lk;

    f32x4 acc[4] = {{0,0,0,0},{0,0,0,0},{0,0,0,0},{0,0,0,0}};
    const bf16x8 zfrag = {0,0,0,0,0,0,0,0};

#pragma unroll 3
    for (int tap = 0; tap < 9; ++tap) {
        // LDS row = tpix + off + HALO; off = (tap/3-1)*56 + (tap%3-1)
        const int row = tpix + (tap / 3) * WSZ + (tap % 3);
        const bool valid = (vmask >> tap) & 1u;
        const int rbase = row * 64;
        const int rsw = row & 7;
#pragma unroll
        for (int half = 0; half < 2; ++half) {
            const int chunk = (4 * half + lk) ^ rsw;
            bf16x8 a = *reinterpret_cast<const bf16x8*>(&xs[rbase + chunk * 8]);
            a = valid ? a : zfrag;
            const unsigned short* wp = wb + tap * 64 + half * 32;
            bf16x8 b0 = *reinterpret_cast<const bf16x8*>(wp);
            bf16x8 b1 = *reinterpret_cast<const bf16x8*>(wp + 16 * KTOT);
            bf16x8 b2 = *reinterpret_cast<const bf16x8*>(wp + 32 * KTOT);
            bf16x8 b3 = *reinterpret_cast<const bf16x8*>(wp + 48 * KTOT);
            acc[0] = __builtin_amdgcn_mfma_f32_16x16x32_bf16(a, b0, acc[0], 0, 0, 0);
            acc[1] = __builtin_amdgcn_mfma_f32_16x16x32_bf16(a, b1, acc[1], 0, 0, 0);
            acc[2] = __builtin_amdgcn_mfma_f32_16x16x32_bf16(a, b2, acc[2], 0, 0, 0);
            acc[3] = __builtin_amdgcn_mfma_f32_16x16x32_bf16(a, b3, acc[3], 0, 0, 0);
        }
    }

    // D: row = 4*lk + r (pixel), col = lrow (out_ch offset) -> 4 consecutive pixels/lane
    const int pstore = p0 + pg * 16 + 4 * lk;
#pragma unroll
    for (int bg = 0; bg < 4; ++bg) {
        const int o = og * 64 + bg * 16 + lrow;
        f32x4 r = acc[bg] + bias[o];
        *reinterpret_cast<f32x4*>(&out[((size_t)(b * OC + o)) * HW + pstore]) = r;
    }
}

extern "C" void kernel_launch(void* const* d_in, const int* in_sizes, int n_in,
                              void* d_out, int out_size, void* d_ws, size_t ws_size,
                              hipStream_t stream) {
    const float* x    = (const float*)d_in[0];
    const float* W    = (const float*)d_in[1];
    const float* bias = (const float*)d_in[2];
    float* out        = (float*)d_out;
    unsigned short* Wb = (unsigned short*)d_ws;   // 128*576*2 = 147456 B

    wcvt_kernel<<<(OC * KTOT + 255) / 256, 256, 0, stream>>>(W, Wb);
    dim3 grid(HW / PTILE, BATCH, 1);              // (49, 4)
    conv_mfma_kernel<<<grid, 512, 0, stream>>>(x, Wb, bias, out);
}